// Round 1
// baseline (1290.183 us; speedup 1.0000x reference)
//
#include <hip/hip_runtime.h>
#include <hip/hip_bf16.h>
#include <cstddef>
#include <cstdint>

#define D 128
#define BN_EPS 1e-5f

// ---------------- CSR build ----------------
__global__ void k_zero_ints(int* p, int n) {
    int i = blockIdx.x * blockDim.x + threadIdx.x;
    if (i < n) p[i] = 0;
}

__global__ void k_zero_f(float* p, int n) {
    int i = blockIdx.x * blockDim.x + threadIdx.x;
    if (i < n) p[i] = 0.f;
}

__global__ void k_hist(const int* __restrict__ dst, int E, int* __restrict__ counts) {
    int e = blockIdx.x * blockDim.x + threadIdx.x;
    if (e < E) atomicAdd(&counts[dst[e]], 1);
}

// exclusive scan over counts, chunk = 1024 per block (256 thr x 4 elems)
__global__ __launch_bounds__(256) void k_scan1(const int* __restrict__ counts, int n,
                                               int* __restrict__ out, int* __restrict__ blocksum) {
    __shared__ int lds[256];
    int tid = threadIdx.x;
    int base = blockIdx.x * 1024 + tid * 4;
    int c[4];
#pragma unroll
    for (int j = 0; j < 4; ++j) c[j] = (base + j < n) ? counts[base + j] : 0;
    int s = c[0] + c[1] + c[2] + c[3];
    lds[tid] = s;
    __syncthreads();
    for (int off = 1; off < 256; off <<= 1) {
        int v = (tid >= off) ? lds[tid - off] : 0;
        __syncthreads();
        lds[tid] += v;
        __syncthreads();
    }
    int run = lds[tid] - s;  // exclusive within block
#pragma unroll
    for (int j = 0; j < 4; ++j) {
        if (base + j < n) out[base + j] = run;
        run += c[j];
    }
    if (tid == 255) blocksum[blockIdx.x] = lds[255];
}

__global__ __launch_bounds__(128) void k_scan2(const int* __restrict__ blocksum, int nb,
                                               int* __restrict__ blockscan) {
    __shared__ int lds[128];
    int tid = threadIdx.x;
    int s = (tid < nb) ? blocksum[tid] : 0;
    lds[tid] = s;
    __syncthreads();
    for (int off = 1; off < 128; off <<= 1) {
        int v = (tid >= off) ? lds[tid - off] : 0;
        __syncthreads();
        lds[tid] += v;
        __syncthreads();
    }
    if (tid < nb) blockscan[tid] = lds[tid] - s;
}

__global__ void k_scan3(int* __restrict__ row_start, const int* __restrict__ blockscan, int n,
                        int* __restrict__ cursor) {
    int i = blockIdx.x * blockDim.x + threadIdx.x;
    if (i < n) {
        int v = row_start[i] + blockscan[i >> 10];
        row_start[i] = v;
        cursor[i] = v;
    }
}

__global__ void k_fill(const int* __restrict__ src, const int* __restrict__ dst, int E,
                       int* __restrict__ cursor, int* __restrict__ col_idx) {
    int e = blockIdx.x * blockDim.x + threadIdx.x;
    if (e < E) {
        int pos = atomicAdd(&cursor[dst[e]], 1);
        col_idx[pos] = src[e];
    }
}

// ---------------- gather: agg[n] = x[n] + sum_{j in N(n)} x[j] ----------------
// one 64-lane wave per node, float2 per lane (64*8B = 512B row)
__global__ __launch_bounds__(256) void k_gather(const float* __restrict__ x,
                                                const int* __restrict__ row_start,
                                                const int* __restrict__ row_end,
                                                const int* __restrict__ col_idx, int n,
                                                float* __restrict__ agg) {
    int node = blockIdx.x * 4 + (threadIdx.x >> 6);
    if (node >= n) return;
    int lane = threadIdx.x & 63;
    size_t co = (size_t)lane * 2;
    float2 acc = *(const float2*)&x[(size_t)node * D + co];
    int s = row_start[node], e = row_end[node];
    for (int j = s; j < e; ++j) {
        int c = col_idx[j];
        float2 v = *(const float2*)&x[(size_t)c * D + co];
        acc.x += v.x;
        acc.y += v.y;
    }
    *(float2*)&agg[(size_t)node * D + co] = acc;
}

// ---------------- GEMM: out = relu(A @ W + bias), optional BN stats ----------------
// block: 128 rows x 128 cols, 512 threads, each thread 4 rows x 8 cols
template <bool DO_STATS>
__global__ __launch_bounds__(512) void k_gemm(const float* __restrict__ A,
                                              const float* __restrict__ W,
                                              const float* __restrict__ bias,
                                              float* __restrict__ out, int n,
                                              float* __restrict__ stats) {
    __shared__ float xs[128][132];   // A tile, padded (+4 floats keeps float4 alignment)
    __shared__ float wsm[128][128];  // W tile [k][c]
    int tid = threadIdx.x;
    int rb = blockIdx.x * 128;

#pragma unroll
    for (int i = 0; i < 8; ++i) {
        int idx = (i * 512 + tid) * 4;
        int k = idx >> 7, c = idx & 127;
        *(float4*)&wsm[k][c] = *(const float4*)&W[idx];
    }
#pragma unroll
    for (int i = 0; i < 8; ++i) {
        int idx = (i * 512 + tid) * 4;
        int r = idx >> 7, k = idx & 127;
        float4 v = make_float4(0.f, 0.f, 0.f, 0.f);
        if (rb + r < n) v = *(const float4*)&A[(size_t)(rb + r) * D + k];
        *(float4*)&xs[r][k] = v;
    }
    __syncthreads();

    const int tc = tid & 15, tr = tid >> 4;  // tc 0..15, tr 0..31
    const int c0 = tc * 8, r0 = tr * 4;
    float acc[4][8];
#pragma unroll
    for (int i = 0; i < 4; ++i)
#pragma unroll
        for (int j = 0; j < 8; ++j) acc[i][j] = 0.f;

#pragma unroll 4
    for (int k = 0; k < 128; ++k) {
        float4 b0 = *(const float4*)&wsm[k][c0];
        float4 b1 = *(const float4*)&wsm[k][c0 + 4];
        float bb[8] = {b0.x, b0.y, b0.z, b0.w, b1.x, b1.y, b1.z, b1.w};
        float aa[4] = {xs[r0 + 0][k], xs[r0 + 1][k], xs[r0 + 2][k], xs[r0 + 3][k]};
#pragma unroll
        for (int i = 0; i < 4; ++i)
#pragma unroll
            for (int j = 0; j < 8; ++j) acc[i][j] = fmaf(aa[i], bb[j], acc[i][j]);
    }

    float bcol[8];
#pragma unroll
    for (int j = 0; j < 8; ++j) bcol[j] = bias[c0 + j];
    float csum[8], csq[8];
#pragma unroll
    for (int j = 0; j < 8; ++j) { csum[j] = 0.f; csq[j] = 0.f; }

#pragma unroll
    for (int i = 0; i < 4; ++i) {
        int r = rb + r0 + i;
        if (r < n) {
            float o[8];
#pragma unroll
            for (int j = 0; j < 8; ++j) {
                float v = fmaxf(acc[i][j] + bcol[j], 0.f);
                o[j] = v;
                if (DO_STATS) {
                    csum[j] += v;
                    csq[j] = fmaf(v, v, csq[j]);
                }
            }
            float4* op = (float4*)&out[(size_t)r * D + c0];
            op[0] = make_float4(o[0], o[1], o[2], o[3]);
            op[1] = make_float4(o[4], o[5], o[6], o[7]);
        }
    }

    if (DO_STATS) {
        __syncthreads();  // done with xs; reuse as reduction scratch
        float* colsum = &xs[0][0];
        float* colsq = &xs[4][0];
        if (tid < 128) colsum[tid] = 0.f;
        if (tid >= 256 && tid < 384) colsq[tid - 256] = 0.f;
        __syncthreads();
#pragma unroll
        for (int j = 0; j < 8; ++j) {
            atomicAdd(&colsum[c0 + j], csum[j]);
            atomicAdd(&colsq[c0 + j], csq[j]);
        }
        __syncthreads();
        if (tid < 128) atomicAdd(&stats[tid], colsum[tid]);
        else if (tid < 256) atomicAdd(&stats[tid], colsq[tid - 128]);
    }
}

// ---------------- BN finalize: per-column affine ----------------
__global__ __launch_bounds__(128) void k_bnfin(const float* __restrict__ stats,
                                               const float* __restrict__ gamma,
                                               const float* __restrict__ beta, float n_inv,
                                               float* __restrict__ ss) {
    int c = threadIdx.x;
    float mean = stats[c] * n_inv;
    float var = stats[c + 128] * n_inv - mean * mean;
    var = fmaxf(var, 0.f);
    float a = gamma[c] * rsqrtf(var + BN_EPS);
    float b = beta[c] - mean * a;
    ss[c] = a;
    ss[c + 128] = b;
}

__global__ void k_norm(const float* __restrict__ h, const float* __restrict__ ss, int total4,
                       float* __restrict__ out) {
    int i = blockIdx.x * blockDim.x + threadIdx.x;
    if (i >= total4) return;
    size_t off = (size_t)i * 4;
    float4 v = *(const float4*)&h[off];
    int c = (int)(off & (D - 1));
    float4 a = *(const float4*)&ss[c];
    float4 b = *(const float4*)&ss[128 + c];
    v.x = fmaf(v.x, a.x, b.x);
    v.y = fmaf(v.y, a.y, b.y);
    v.z = fmaf(v.z, a.z, b.z);
    v.w = fmaf(v.w, a.w, b.w);
    *(float4*)&out[off] = v;
}

extern "C" void kernel_launch(void* const* d_in, const int* in_sizes, int n_in, void* d_out,
                              int out_size, void* d_ws, size_t ws_size, hipStream_t stream) {
    const float* x = (const float*)d_in[0];
    const int* esrc = (const int*)d_in[1];
    const int* edst = (const int*)d_in[2];
    const float* W1 = (const float*)d_in[3];
    const float* b1 = (const float*)d_in[4];
    const float* W2 = (const float*)d_in[5];
    const float* b2 = (const float*)d_in[6];
    const float* gamma = (const float*)d_in[7];
    const float* beta = (const float*)d_in[8];

    const int N = in_sizes[0] / D;
    const int E = in_sizes[1];
    const int L = in_sizes[3] / (D * D);
    const size_t nd = (size_t)N * D;

    // workspace layout (~110 MB)
    char* ws = (char*)d_ws;
    float* ws0 = (float*)ws;            ws += nd * sizeof(float);
    float* ws1 = (float*)ws;            ws += nd * sizeof(float);
    int* counts = (int*)ws;             ws += (size_t)N * sizeof(int);  // becomes cursor / row_end
    int* row_start = (int*)ws;          ws += (size_t)N * sizeof(int);
    int* col_idx = (int*)ws;            ws += (size_t)E * sizeof(int);
    int* blocksum = (int*)ws;           ws += 512;
    int* blockscan = (int*)ws;          ws += 512;
    float* stats = (float*)ws;          ws += 1024;
    float* ss = (float*)ws;             ws += 1024;
    float* out = (float*)d_out;

    // ---- CSR build (once; edge list shared by all layers) ----
    int nb1024 = (N + 1023) / 1024;
    k_zero_ints<<<(N + 255) / 256, 256, 0, stream>>>(counts, N);
    k_hist<<<(E + 255) / 256, 256, 0, stream>>>(edst, E, counts);
    k_scan1<<<nb1024, 256, 0, stream>>>(counts, N, row_start, blocksum);
    k_scan2<<<1, 128, 0, stream>>>(blocksum, nb1024, blockscan);
    k_scan3<<<(N + 255) / 256, 256, 0, stream>>>(row_start, blockscan, N, counts);
    k_fill<<<(E + 255) / 256, 256, 0, stream>>>(esrc, edst, E, counts, col_idx);
    // counts[i] now == row_end[i]

    const int gb = (N + 127) / 128;
    const float* P = x;
    for (int l = 0; l < L; ++l) {
        k_gather<<<(N + 3) / 4, 256, 0, stream>>>(P, row_start, counts, col_idx, N, ws0);
        k_gemm<false><<<gb, 512, 0, stream>>>(ws0, W1 + (size_t)l * D * D, b1 + (size_t)l * D,
                                              out, N, nullptr);
        k_zero_f<<<1, 256, 0, stream>>>(stats, 256);
        k_gemm<true><<<gb, 512, 0, stream>>>(out, W2 + (size_t)l * D * D, b2 + (size_t)l * D,
                                             ws0, N, stats);
        k_bnfin<<<1, 128, 0, stream>>>(stats, gamma + (size_t)l * D, beta + (size_t)l * D,
                                       1.0f / (float)N, ss);
        float* xn = (l == L - 1) ? out : ws1;
        k_norm<<<(int)((nd / 4 + 255) / 256), 256, 0, stream>>>(ws0, ss, (int)(nd / 4), xn);
        P = ws1;
    }
}

// Round 3
// 643.065 us; speedup vs baseline: 2.0063x; 2.0063x over previous
//
#include <hip/hip_runtime.h>
#include <cstddef>
#include <cstdint>

#define D 128
#define BN_EPS 1e-5f

typedef _Float16 f16x8 __attribute__((ext_vector_type(8)));
typedef float f32x4 __attribute__((ext_vector_type(4)));

__device__ __forceinline__ ushort f2h(float f) {
    _Float16 h = (_Float16)f;  // v_cvt_f16_f32, RTN
    ushort s;
    __builtin_memcpy(&s, &h, 2);
    return s;
}
__device__ __forceinline__ float hlo(uint v) {
    ushort s = (ushort)(v & 0xffffu);
    _Float16 h;
    __builtin_memcpy(&h, &s, 2);
    return (float)h;
}
__device__ __forceinline__ float hhi(uint v) {
    ushort s = (ushort)(v >> 16);
    _Float16 h;
    __builtin_memcpy(&h, &s, 2);
    return (float)h;
}

// ---------------- CSR build ----------------
__global__ void k_zero_ints(int* p, int n) {
    int i = blockIdx.x * blockDim.x + threadIdx.x;
    if (i < n) p[i] = 0;
}

__global__ void k_zero_f(float* p, int n) {
    int i = blockIdx.x * blockDim.x + threadIdx.x;
    if (i < n) p[i] = 0.f;
}

__global__ void k_hist(const int* __restrict__ dst, int E, int* __restrict__ counts) {
    int e = blockIdx.x * blockDim.x + threadIdx.x;
    if (e < E) atomicAdd(&counts[dst[e]], 1);
}

__global__ __launch_bounds__(256) void k_scan1(const int* __restrict__ counts, int n,
                                               int* __restrict__ out, int* __restrict__ blocksum) {
    __shared__ int lds[256];
    int tid = threadIdx.x;
    int base = blockIdx.x * 1024 + tid * 4;
    int c[4];
#pragma unroll
    for (int j = 0; j < 4; ++j) c[j] = (base + j < n) ? counts[base + j] : 0;
    int s = c[0] + c[1] + c[2] + c[3];
    lds[tid] = s;
    __syncthreads();
    for (int off = 1; off < 256; off <<= 1) {
        int v = (tid >= off) ? lds[tid - off] : 0;
        __syncthreads();
        lds[tid] += v;
        __syncthreads();
    }
    int run = lds[tid] - s;
#pragma unroll
    for (int j = 0; j < 4; ++j) {
        if (base + j < n) out[base + j] = run;
        run += c[j];
    }
    if (tid == 255) blocksum[blockIdx.x] = lds[255];
}

__global__ __launch_bounds__(128) void k_scan2(const int* __restrict__ blocksum, int nb,
                                               int* __restrict__ blockscan) {
    __shared__ int lds[128];
    int tid = threadIdx.x;
    int s = (tid < nb) ? blocksum[tid] : 0;
    lds[tid] = s;
    __syncthreads();
    for (int off = 1; off < 128; off <<= 1) {
        int v = (tid >= off) ? lds[tid - off] : 0;
        __syncthreads();
        lds[tid] += v;
        __syncthreads();
    }
    if (tid < nb) blockscan[tid] = lds[tid] - s;
}

__global__ void k_scan3(int* __restrict__ row_start, const int* __restrict__ blockscan, int n,
                        int* __restrict__ cursor) {
    int i = blockIdx.x * blockDim.x + threadIdx.x;
    if (i < n) {
        int v = row_start[i] + blockscan[i >> 10];
        row_start[i] = v;
        cursor[i] = v;
    }
}

__global__ void k_fill(const int* __restrict__ src, const int* __restrict__ dst, int E,
                       int* __restrict__ cursor, int* __restrict__ col_idx) {
    int e = blockIdx.x * blockDim.x + threadIdx.x;
    if (e < E) {
        int pos = atomicAdd(&cursor[dst[e]], 1);
        col_idx[pos] = src[e];
    }
}

// ---------------- fp32 -> fp16 convert ----------------
__global__ void k_convert(const float* __restrict__ x, uint* __restrict__ xh, int nd8) {
    int i = blockIdx.x * blockDim.x + threadIdx.x;
    if (i >= nd8) return;
    size_t off = (size_t)i * 8;
    const float4* p = (const float4*)(x + off);
    float4 v0 = p[0], v1 = p[1];
    uint4 o;
    o.x = (uint)f2h(v0.x) | ((uint)f2h(v0.y) << 16);
    o.y = (uint)f2h(v0.z) | ((uint)f2h(v0.w) << 16);
    o.z = (uint)f2h(v1.x) | ((uint)f2h(v1.y) << 16);
    o.w = (uint)f2h(v1.z) | ((uint)f2h(v1.w) << 16);
    *(uint4*)(xh + off / 2) = o;
}

// ---------------- weight prep: fp32 W[k][c] -> fp16 Wt[c][k] ----------------
__global__ __launch_bounds__(256) void k_prep_w(const float* __restrict__ W,
                                                ushort* __restrict__ Wt) {
    const float* src = W + (size_t)blockIdx.x * D * D;
    ushort* dst = Wt + (size_t)blockIdx.x * D * D;
#pragma unroll
    for (int i = 0; i < 64; ++i) {
        int idx = i * 256 + threadIdx.x;
        int k = idx >> 7, c = idx & 127;
        dst[c * D + k] = f2h(src[idx]);
    }
}

// ---------------- gather: agg[n] = x[n] + sum_{j in N(n)} x[j]  (fp16 in/out) ----------------
__global__ __launch_bounds__(256) void k_gather(const uint* __restrict__ xh,
                                                const int* __restrict__ rs,
                                                const int* __restrict__ re,
                                                const int* __restrict__ col, int n,
                                                uint* __restrict__ agg) {
    int node = blockIdx.x * 4 + (threadIdx.x >> 6);
    if (node >= n) return;
    int lane = threadIdx.x & 63;
    const uint* xr = xh + lane;
    uint sv = xr[(size_t)node * 64];
    float ax = hlo(sv), ay = hhi(sv);
    int j = rs[node], e = re[node];
    for (; j + 4 <= e; j += 4) {
        int c0 = col[j], c1 = col[j + 1], c2 = col[j + 2], c3 = col[j + 3];
        uint v0 = xr[(size_t)c0 * 64];
        uint v1 = xr[(size_t)c1 * 64];
        uint v2 = xr[(size_t)c2 * 64];
        uint v3 = xr[(size_t)c3 * 64];
        ax += hlo(v0) + hlo(v1) + hlo(v2) + hlo(v3);
        ay += hhi(v0) + hhi(v1) + hhi(v2) + hhi(v3);
    }
    for (; j < e; ++j) {
        uint v = xr[(size_t)col[j] * 64];
        ax += hlo(v);
        ay += hhi(v);
    }
    agg[(size_t)node * 64 + lane] = (uint)f2h(ax) | ((uint)f2h(ay) << 16);
}

// ---------------- fused MLP: h2 = relu(relu(agg@W1+b1)@W2+b2), BN stats ----------------
// 256 threads = 4 waves (2x2), 128-row tile, full K=128, mfma 16x16x32 f16
__global__ __launch_bounds__(256) void k_mlp(const ushort* __restrict__ aggh,
                                             const ushort* __restrict__ Wt1,
                                             const float* __restrict__ b1,
                                             const ushort* __restrict__ Wt2,
                                             const float* __restrict__ b2,
                                             float* __restrict__ h2,
                                             float* __restrict__ stats_mid, int n) {
    __shared__ ushort As[D * D];  // 32 KB, XOR-swizzled by 16B chunk
    __shared__ float sred[256];
    const int tid = threadIdx.x;
    const int rb = blockIdx.x * 128;
    sred[tid] = 0.f;

    // stage agg tile (fp16), swizzle chunk ^= row&15
#pragma unroll
    for (int i = 0; i < 8; ++i) {
        int idx = i * 256 + tid;
        int row = idx >> 4, ch = idx & 15;
        uint4 v = make_uint4(0, 0, 0, 0);
        if (rb + row < n) v = *(const uint4*)(aggh + (size_t)(rb + row) * D + ch * 8);
        *(uint4*)(As + row * D + ((ch ^ (row & 15)) << 3)) = v;
    }
    __syncthreads();

    const int lane = tid & 63, wid = tid >> 6;
    const int wm = wid >> 1, wn = wid & 1;
    const int l15 = lane & 15, lk = lane >> 4;

    f32x4 acc[4][4];
#pragma unroll
    for (int m = 0; m < 4; ++m)
#pragma unroll
        for (int nn = 0; nn < 4; ++nn) acc[m][nn] = (f32x4){0.f, 0.f, 0.f, 0.f};

    // GEMM1: A from LDS, B from global Wt1 (L1/L2-resident, 32KB)
#pragma unroll
    for (int ks = 0; ks < 4; ++ks) {
        f16x8 a[4], b[4];
        int k0 = ks * 32 + lk * 8;
#pragma unroll
        for (int m = 0; m < 4; ++m) {
            int row = wm * 64 + m * 16 + l15;
            a[m] = *(const f16x8*)(As + row * D + (((ks * 4 + lk) ^ l15) << 3));
        }
#pragma unroll
        for (int nn = 0; nn < 4; ++nn) {
            int c = wn * 64 + nn * 16 + l15;
            b[nn] = *(const f16x8*)(Wt1 + (size_t)c * D + k0);
        }
#pragma unroll
        for (int m = 0; m < 4; ++m)
#pragma unroll
            for (int nn = 0; nn < 4; ++nn)
                acc[m][nn] =
                    __builtin_amdgcn_mfma_f32_16x16x32_f16(a[m], b[nn], acc[m][nn], 0, 0, 0);
    }
    __syncthreads();  // everyone done reading As

    // epilogue1: h1 = relu(acc + b1) -> back into As (fp16, same swizzle)
    {
        float bc[4];
#pragma unroll
        for (int nn = 0; nn < 4; ++nn) bc[nn] = b1[wn * 64 + nn * 16 + l15];
#pragma unroll
        for (int nn = 0; nn < 4; ++nn) {
            int cout = wn * 64 + nn * 16 + l15;
            int chv = cout >> 3, cw = cout & 7;
#pragma unroll
            for (int m = 0; m < 4; ++m)
#pragma unroll
                for (int r = 0; r < 4; ++r) {
                    int row = wm * 64 + m * 16 + lk * 4 + r;
                    float v = fmaxf(acc[m][nn][r] + bc[nn], 0.f);
                    As[row * D + ((chv ^ (row & 15)) << 3) + cw] = f2h(v);
                }
        }
    }
    __syncthreads();

    // GEMM2: A = h1 from LDS, B from global Wt2
#pragma unroll
    for (int m = 0; m < 4; ++m)
#pragma unroll
        for (int nn = 0; nn < 4; ++nn) acc[m][nn] = (f32x4){0.f, 0.f, 0.f, 0.f};
#pragma unroll
    for (int ks = 0; ks < 4; ++ks) {
        f16x8 a[4], b[4];
        int k0 = ks * 32 + lk * 8;
#pragma unroll
        for (int m = 0; m < 4; ++m) {
            int row = wm * 64 + m * 16 + l15;
            a[m] = *(const f16x8*)(As + row * D + (((ks * 4 + lk) ^ l15) << 3));
        }
#pragma unroll
        for (int nn = 0; nn < 4; ++nn) {
            int c = wn * 64 + nn * 16 + l15;
            b[nn] = *(const f16x8*)(Wt2 + (size_t)c * D + k0);
        }
#pragma unroll
        for (int m = 0; m < 4; ++m)
#pragma unroll
            for (int nn = 0; nn < 4; ++nn)
                acc[m][nn] =
                    __builtin_amdgcn_mfma_f32_16x16x32_f16(a[m], b[nn], acc[m][nn], 0, 0, 0);
    }

    // epilogue2: h2 = relu(acc + b2) -> global fp32, + column stats
    {
        float bc[4], cs[4] = {0.f, 0.f, 0.f, 0.f}, cq[4] = {0.f, 0.f, 0.f, 0.f};
#pragma unroll
        for (int nn = 0; nn < 4; ++nn) bc[nn] = b2[wn * 64 + nn * 16 + l15];
#pragma unroll
        for (int nn = 0; nn < 4; ++nn) {
            int c = wn * 64 + nn * 16 + l15;
#pragma unroll
            for (int m = 0; m < 4; ++m) {
                int rbase = rb + wm * 64 + m * 16 + lk * 4;
#pragma unroll
                for (int r = 0; r < 4; ++r) {
                    if (rbase + r < n) {
                        float v = fmaxf(acc[m][nn][r] + bc[nn], 0.f);
                        h2[(size_t)(rbase + r) * D + c] = v;
                        cs[nn] += v;
                        cq[nn] = fmaf(v, v, cq[nn]);
                    }
                }
            }
        }
#pragma unroll
        for (int nn = 0; nn < 4; ++nn) {
            int c = wn * 64 + nn * 16 + l15;
            atomicAdd(&sred[c], cs[nn]);
            atomicAdd(&sred[128 + c], cq[nn]);
        }
    }
    __syncthreads();
    atomicAdd(&stats_mid[(blockIdx.x & 31) * 256 + tid], sred[tid]);
}

// ---------------- BN finalize ----------------
__global__ __launch_bounds__(128) void k_bnfin(const float* __restrict__ sm,
                                               const float* __restrict__ gamma,
                                               const float* __restrict__ beta, float ninv,
                                               float* __restrict__ ss) {
    int c = threadIdx.x;
    float s = 0.f, q = 0.f;
    for (int r = 0; r < 32; ++r) {
        s += sm[r * 256 + c];
        q += sm[r * 256 + 128 + c];
    }
    float mean = s * ninv;
    float var = fmaxf(q * ninv - mean * mean, 0.f);
    float a = gamma[c] * rsqrtf(var + BN_EPS);
    ss[c] = a;
    ss[128 + c] = beta[c] - mean * a;
}

// ---------------- normalize: x_next = a*h2 + b ----------------
template <bool FINAL>
__global__ void k_norm(const float* __restrict__ h, const float* __restrict__ ss, int nd8,
                       float* __restrict__ outf, uint* __restrict__ outh) {
    int i = blockIdx.x * blockDim.x + threadIdx.x;
    if (i >= nd8) return;
    size_t off = (size_t)i * 8;
    int c = (int)(off & (D - 1));
    const float4* hp = (const float4*)(h + off);
    float4 v0 = hp[0], v1 = hp[1];
    float4 a0 = *(const float4*)(ss + c), a1 = *(const float4*)(ss + c + 4);
    float4 b0 = *(const float4*)(ss + 128 + c), b1 = *(const float4*)(ss + 132 + c);
    v0.x = fmaf(v0.x, a0.x, b0.x);
    v0.y = fmaf(v0.y, a0.y, b0.y);
    v0.z = fmaf(v0.z, a0.z, b0.z);
    v0.w = fmaf(v0.w, a0.w, b0.w);
    v1.x = fmaf(v1.x, a1.x, b1.x);
    v1.y = fmaf(v1.y, a1.y, b1.y);
    v1.z = fmaf(v1.z, a1.z, b1.z);
    v1.w = fmaf(v1.w, a1.w, b1.w);
    if (FINAL) {
        *(float4*)(outf + off) = v0;
        *(float4*)(outf + off + 4) = v1;
    } else {
        uint4 o;
        o.x = (uint)f2h(v0.x) | ((uint)f2h(v0.y) << 16);
        o.y = (uint)f2h(v0.z) | ((uint)f2h(v0.w) << 16);
        o.z = (uint)f2h(v1.x) | ((uint)f2h(v1.y) << 16);
        o.w = (uint)f2h(v1.z) | ((uint)f2h(v1.w) << 16);
        *(uint4*)(outh + off / 2) = o;
    }
}

extern "C" void kernel_launch(void* const* d_in, const int* in_sizes, int n_in, void* d_out,
                              int out_size, void* d_ws, size_t ws_size, hipStream_t stream) {
    const float* x = (const float*)d_in[0];
    const int* esrc = (const int*)d_in[1];
    const int* edst = (const int*)d_in[2];
    const float* W1 = (const float*)d_in[3];
    const float* b1 = (const float*)d_in[4];
    const float* W2 = (const float*)d_in[5];
    const float* b2 = (const float*)d_in[6];
    const float* gamma = (const float*)d_in[7];
    const float* beta = (const float*)d_in[8];

    const int N = in_sizes[0] / D;
    const int E = in_sizes[1];
    const int L = in_sizes[3] / (D * D);
    const size_t nd = (size_t)N * D;
    const int nd8 = (int)(nd / 8);

    // workspace layout
    char* ws = (char*)d_ws;
    uint* xh = (uint*)ws;        ws += nd * 2;                    // fp16 activations
    uint* aggh = (uint*)ws;      ws += nd * 2;                    // fp16 agg
    ushort* Wt1 = (ushort*)ws;   ws += (size_t)L * D * D * 2;     // fp16 W1^T
    ushort* Wt2 = (ushort*)ws;   ws += (size_t)L * D * D * 2;     // fp16 W2^T
    int* counts = (int*)ws;      ws += (size_t)N * 4;             // cursor / row_end
    int* row_start = (int*)ws;   ws += (size_t)N * 4;
    int* col_idx = (int*)ws;     ws += (size_t)E * 4;
    int* blocksum = (int*)ws;    ws += 512;
    int* blockscan = (int*)ws;   ws += 512;
    float* stats_mid = (float*)ws; ws += 32 * 256 * 4;
    float* ss = (float*)ws;      ws += 1024;
    float* h2 = (float*)d_out;

    // ---- one-time prep ----
    k_convert<<<(nd8 + 255) / 256, 256, 0, stream>>>(x, xh, nd8);
    k_prep_w<<<L, 256, 0, stream>>>(W1, Wt1);
    k_prep_w<<<L, 256, 0, stream>>>(W2, Wt2);

    int nb1024 = (N + 1023) / 1024;
    k_zero_ints<<<(N + 255) / 256, 256, 0, stream>>>(counts, N);
    k_hist<<<(E + 255) / 256, 256, 0, stream>>>(edst, E, counts);
    k_scan1<<<nb1024, 256, 0, stream>>>(counts, N, row_start, blocksum);
    k_scan2<<<1, 128, 0, stream>>>(blocksum, nb1024, blockscan);
    k_scan3<<<(N + 255) / 256, 256, 0, stream>>>(row_start, blockscan, N, counts);
    k_fill<<<(E + 255) / 256, 256, 0, stream>>>(esrc, edst, E, counts, col_idx);

    const int gb = (N + 127) / 128;
    for (int l = 0; l < L; ++l) {
        k_gather<<<(N + 3) / 4, 256, 0, stream>>>(xh, row_start, counts, col_idx, N, aggh);
        k_zero_f<<<32, 256, 0, stream>>>(stats_mid, 32 * 256);
        k_mlp<<<gb, 256, 0, stream>>>((const ushort*)aggh, Wt1 + (size_t)l * D * D,
                                      b1 + (size_t)l * D, Wt2 + (size_t)l * D * D,
                                      b2 + (size_t)l * D, h2, stats_mid, N);
        k_bnfin<<<1, 128, 0, stream>>>(stats_mid, gamma + (size_t)l * D, beta + (size_t)l * D,
                                       1.0f / (float)N, ss);
        if (l == L - 1)
            k_norm<true><<<(nd8 + 255) / 256, 256, 0, stream>>>(h2, ss, nd8, h2, nullptr);
        else
            k_norm<false><<<(nd8 + 255) / 256, 256, 0, stream>>>(h2, ss, nd8, nullptr, xh);
    }
}

// Round 4
// 443.603 us; speedup vs baseline: 2.9084x; 1.4496x over previous
//
#include <hip/hip_runtime.h>
#include <cstddef>
#include <cstdint>

#define D 128
#define BN_EPS 1e-5f
#define BKT_SH 9               // 512 nodes per bucket
#define BKT_N 512
#define ABLK 256               // blocks in bucket passes

typedef _Float16 f16x8 __attribute__((ext_vector_type(8)));
typedef float f32x4 __attribute__((ext_vector_type(4)));

__device__ __forceinline__ ushort f2h(float f) {
    _Float16 h = (_Float16)f;
    ushort s;
    __builtin_memcpy(&s, &h, 2);
    return s;
}
__device__ __forceinline__ float hlo(uint v) {
    ushort s = (ushort)(v & 0xffffu);
    _Float16 h;
    __builtin_memcpy(&h, &s, 2);
    return (float)h;
}
__device__ __forceinline__ float hhi(uint v) {
    ushort s = (ushort)(v >> 16);
    _Float16 h;
    __builtin_memcpy(&h, &s, 2);
    return (float)h;
}

__global__ void k_zero_f(float* p, int n) {
    int i = blockIdx.x * blockDim.x + threadIdx.x;
    if (i < n) p[i] = 0.f;
}

__global__ void k_init_ss(float* ss) {
    int t = threadIdx.x;
    ss[t] = 1.f;
    ss[128 + t] = 0.f;
}

// ---------------- bucketed CSR build (no global atomics) ----------------
// A1: per-block histogram of dst buckets
__global__ __launch_bounds__(256) void k_bcount(const int* __restrict__ dst, int E, int CH,
                                                int nbkt, int* __restrict__ bcnt) {
    __shared__ int h[256];
    int tid = threadIdx.x;
    h[tid] = 0;
    __syncthreads();
    int s = blockIdx.x * CH, e = s + CH;
    if (e > E) e = E;
    for (int i = s + tid; i < e; i += 256) atomicAdd(&h[dst[i] >> BKT_SH], 1);
    __syncthreads();
    if (tid < nbkt) bcnt[tid * ABLK + blockIdx.x] = h[tid];
}

// A2: per-bucket intra scan + bucket bases
__global__ __launch_bounds__(256) void k_bscan(const int* __restrict__ bcnt, int nbkt,
                                               int* __restrict__ boff, int* __restrict__ bbase,
                                               int* __restrict__ row_start, int N, int E) {
    __shared__ int tot[256];
    int b = threadIdx.x;
    int t = 0;
    if (b < nbkt) {
        for (int i = 0; i < ABLK; ++i) {
            boff[b * ABLK + i] = t;
            t += bcnt[b * ABLK + i];
        }
    }
    tot[b] = t;
    __syncthreads();
    int v = t;
    for (int off = 1; off < 256; off <<= 1) {
        int u = (b >= off) ? tot[b - off] : 0;
        __syncthreads();
        tot[b] += u;
        __syncthreads();
    }
    if (b < nbkt) bbase[b] = tot[b] - v;
    if (b == 0) {
        bbase[nbkt] = E;
        row_start[N] = E;
    }
}

// A3: scatter packed edges into bucket-grouped staging (deterministic offsets per block)
__global__ __launch_bounds__(256) void k_bscatter(const int* __restrict__ src,
                                                  const int* __restrict__ dst, int E, int CH,
                                                  int nbkt, const int* __restrict__ boff,
                                                  const int* __restrict__ bbase,
                                                  uint* __restrict__ staged) {
    __shared__ int cur[256];
    int tid = threadIdx.x;
    if (tid < nbkt) cur[tid] = bbase[tid] + boff[tid * ABLK + blockIdx.x];
    __syncthreads();
    int s = blockIdx.x * CH, e = s + CH;
    if (e > E) e = E;
    for (int i = s + tid; i < e; i += 256) {
        int d = dst[i];
        int b = d >> BKT_SH;
        int pos = atomicAdd(&cur[b], 1);
        staged[pos] = ((uint)(d & (BKT_N - 1)) << 23) | (uint)src[i];
    }
}

// B: per-bucket local count/scan -> row_start + col_idx fill (L2-local writes)
__global__ __launch_bounds__(256) void k_bfill(const uint* __restrict__ staged,
                                               const int* __restrict__ bbase, int N,
                                               int* __restrict__ row_start,
                                               int* __restrict__ col_idx) {
    __shared__ int cnt[BKT_N];
    __shared__ int sc[256];
    __shared__ int cur[BKT_N];
    int b = blockIdx.x, tid = threadIdx.x;
    cnt[tid] = 0;
    cnt[tid + 256] = 0;
    __syncthreads();
    int ebase = bbase[b], eend = bbase[b + 1];
    for (int i = ebase + tid; i < eend; i += 256) atomicAdd(&cnt[staged[i] >> 23], 1);
    __syncthreads();
    int c0 = cnt[2 * tid], c1 = cnt[2 * tid + 1], s = c0 + c1;
    sc[tid] = s;
    __syncthreads();
    for (int off = 1; off < 256; off <<= 1) {
        int u = (tid >= off) ? sc[tid - off] : 0;
        __syncthreads();
        sc[tid] += u;
        __syncthreads();
    }
    int ex = sc[tid] - s;
    int g0 = (b << BKT_SH) + 2 * tid;
    int p0 = ebase + ex, p1 = ebase + ex + c0;
    cur[2 * tid] = p0;
    cur[2 * tid + 1] = p1;
    if (g0 < N) row_start[g0] = p0;
    if (g0 + 1 < N) row_start[g0 + 1] = p1;
    __syncthreads();
    for (int i = ebase + tid; i < eend; i += 256) {
        uint w = staged[i];
        int pos = atomicAdd(&cur[w >> 23], 1);
        col_idx[pos] = (int)(w & 0x7FFFFFu);
    }
}

// ---------------- fp32 -> fp16 convert ----------------
__global__ void k_convert(const float* __restrict__ x, uint* __restrict__ xh, int nd8) {
    int i = blockIdx.x * blockDim.x + threadIdx.x;
    if (i >= nd8) return;
    size_t off = (size_t)i * 8;
    const float4* p = (const float4*)(x + off);
    float4 v0 = p[0], v1 = p[1];
    uint4 o;
    o.x = (uint)f2h(v0.x) | ((uint)f2h(v0.y) << 16);
    o.y = (uint)f2h(v0.z) | ((uint)f2h(v0.w) << 16);
    o.z = (uint)f2h(v1.x) | ((uint)f2h(v1.y) << 16);
    o.w = (uint)f2h(v1.z) | ((uint)f2h(v1.w) << 16);
    *(uint4*)(xh + off / 2) = o;
}

// ---------------- weight prep: fp32 W[k][c] -> fp16 Wt[c][k] ----------------
__global__ __launch_bounds__(256) void k_prep_w(const float* __restrict__ W,
                                                ushort* __restrict__ Wt) {
    const float* src = W + (size_t)blockIdx.x * D * D;
    ushort* dst = Wt + (size_t)blockIdx.x * D * D;
#pragma unroll
    for (int i = 0; i < 64; ++i) {
        int idx = i * 256 + threadIdx.x;
        int k = idx >> 7, c = idx & 127;
        dst[c * D + k] = f2h(src[idx]);
    }
}

// ---------------- gather: agg_raw[n] = x[n] + sum_{j in N(n)} x[j]  (fp16) ----------------
// 4 nodes per wave, 16 lanes x uint4 per row, unroll 2
__global__ __launch_bounds__(256) void k_gather(const uint* __restrict__ xh,
                                                const int* __restrict__ rs,
                                                const int* __restrict__ col, int n,
                                                uint* __restrict__ agg) {
    int tid = threadIdx.x;
    int l16 = tid & 15;
    int node = blockIdx.x * 16 + ((tid >> 6) << 2) + ((tid & 63) >> 4);
    if (node >= n) return;
    const uint4* xr = (const uint4*)xh + l16;  // row r at xr[r*16]
    uint4 v = xr[(size_t)node * 16];
    float a0 = hlo(v.x), a1 = hhi(v.x), a2 = hlo(v.y), a3 = hhi(v.y);
    float a4 = hlo(v.z), a5 = hhi(v.z), a6 = hlo(v.w), a7 = hhi(v.w);
    int j = rs[node], e = rs[node + 1];
    for (; j + 2 <= e; j += 2) {
        int c0 = col[j], c1 = col[j + 1];
        uint4 u = xr[(size_t)c0 * 16];
        uint4 w = xr[(size_t)c1 * 16];
        a0 += hlo(u.x) + hlo(w.x);
        a1 += hhi(u.x) + hhi(w.x);
        a2 += hlo(u.y) + hlo(w.y);
        a3 += hhi(u.y) + hhi(w.y);
        a4 += hlo(u.z) + hlo(w.z);
        a5 += hhi(u.z) + hhi(w.z);
        a6 += hlo(u.w) + hlo(w.w);
        a7 += hhi(u.w) + hhi(w.w);
    }
    if (j < e) {
        uint4 u = xr[(size_t)col[j] * 16];
        a0 += hlo(u.x);
        a1 += hhi(u.x);
        a2 += hlo(u.y);
        a3 += hhi(u.y);
        a4 += hlo(u.z);
        a5 += hhi(u.z);
        a6 += hlo(u.w);
        a7 += hhi(u.w);
    }
    uint4 o;
    o.x = (uint)f2h(a0) | ((uint)f2h(a1) << 16);
    o.y = (uint)f2h(a2) | ((uint)f2h(a3) << 16);
    o.z = (uint)f2h(a4) | ((uint)f2h(a5) << 16);
    o.w = (uint)f2h(a6) | ((uint)f2h(a7) << 16);
    ((uint4*)agg)[(size_t)node * 16 + l16] = o;
}

// ---------------- fused MLP with deferred BN affine ----------------
// input u = a (.) agg_raw + cnt*b  (prev layer's BN affine, linearity of aggregation)
// h2 = relu(relu(u@W1+b1)@W2+b2) stored fp16, + column stats
__global__ __launch_bounds__(256) void k_mlp(const ushort* __restrict__ aggh,
                                             const int* __restrict__ rs,
                                             const float* __restrict__ ssin,
                                             const ushort* __restrict__ Wt1,
                                             const float* __restrict__ b1,
                                             const ushort* __restrict__ Wt2,
                                             const float* __restrict__ b2,
                                             uint* __restrict__ h2,
                                             float* __restrict__ stats_mid, int n) {
    __shared__ ushort As[D * D];  // 32 KB, XOR-swizzled by 16B chunk
    __shared__ float sred[256];
    const int tid = threadIdx.x;
    const int rb = blockIdx.x * 128;
    sred[tid] = 0.f;

    // stage: u = a*raw + cnt*b, fp16, swizzled
#pragma unroll
    for (int i = 0; i < 8; ++i) {
        int idx = i * 256 + tid;
        int row = idx >> 4, ch = idx & 15;
        int g = rb + row;
        uint4 o = make_uint4(0, 0, 0, 0);
        if (g < n) {
            uint4 v = *(const uint4*)(aggh + (size_t)g * D + ch * 8);
            float cntf = (float)(rs[g + 1] - rs[g] + 1);
            const float4* ap = (const float4*)(ssin + ch * 8);
            const float4* bp = (const float4*)(ssin + 128 + ch * 8);
            float4 A0 = ap[0], A1 = ap[1], B0 = bp[0], B1 = bp[1];
            float r0 = fmaf(A0.x, hlo(v.x), cntf * B0.x);
            float r1 = fmaf(A0.y, hhi(v.x), cntf * B0.y);
            float r2 = fmaf(A0.z, hlo(v.y), cntf * B0.z);
            float r3 = fmaf(A0.w, hhi(v.y), cntf * B0.w);
            float r4 = fmaf(A1.x, hlo(v.z), cntf * B1.x);
            float r5 = fmaf(A1.y, hhi(v.z), cntf * B1.y);
            float r6 = fmaf(A1.z, hlo(v.w), cntf * B1.z);
            float r7 = fmaf(A1.w, hhi(v.w), cntf * B1.w);
            o.x = (uint)f2h(r0) | ((uint)f2h(r1) << 16);
            o.y = (uint)f2h(r2) | ((uint)f2h(r3) << 16);
            o.z = (uint)f2h(r4) | ((uint)f2h(r5) << 16);
            o.w = (uint)f2h(r6) | ((uint)f2h(r7) << 16);
        }
        *(uint4*)(As + row * D + ((ch ^ (row & 15)) << 3)) = o;
    }
    __syncthreads();

    const int lane = tid & 63, wid = tid >> 6;
    const int wm = wid >> 1, wn = wid & 1;
    const int l15 = lane & 15, lk = lane >> 4;

    f32x4 acc[4][4];
#pragma unroll
    for (int m = 0; m < 4; ++m)
#pragma unroll
        for (int nn = 0; nn < 4; ++nn) acc[m][nn] = (f32x4){0.f, 0.f, 0.f, 0.f};

    // GEMM1
#pragma unroll
    for (int ks = 0; ks < 4; ++ks) {
        f16x8 a[4], b[4];
        int k0 = ks * 32 + lk * 8;
#pragma unroll
        for (int m = 0; m < 4; ++m) {
            int row = wm * 64 + m * 16 + l15;
            a[m] = *(const f16x8*)(As + row * D + (((ks * 4 + lk) ^ l15) << 3));
        }
#pragma unroll
        for (int nn = 0; nn < 4; ++nn) {
            int c = wn * 64 + nn * 16 + l15;
            b[nn] = *(const f16x8*)(Wt1 + (size_t)c * D + k0);
        }
#pragma unroll
        for (int m = 0; m < 4; ++m)
#pragma unroll
            for (int nn = 0; nn < 4; ++nn)
                acc[m][nn] =
                    __builtin_amdgcn_mfma_f32_16x16x32_f16(a[m], b[nn], acc[m][nn], 0, 0, 0);
    }
    __syncthreads();

    // epilogue1: h1 = relu(acc + b1) -> As (fp16, swizzled)
    {
        float bc[4];
#pragma unroll
        for (int nn = 0; nn < 4; ++nn) bc[nn] = b1[wn * 64 + nn * 16 + l15];
#pragma unroll
        for (int nn = 0; nn < 4; ++nn) {
            int cout = wn * 64 + nn * 16 + l15;
            int chv = cout >> 3, cw = cout & 7;
#pragma unroll
            for (int m = 0; m < 4; ++m)
#pragma unroll
                for (int r = 0; r < 4; ++r) {
                    int row = wm * 64 + m * 16 + lk * 4 + r;
                    float v = fmaxf(acc[m][nn][r] + bc[nn], 0.f);
                    As[row * D + ((chv ^ (row & 15)) << 3) + cw] = f2h(v);
                }
        }
    }
    __syncthreads();

    // GEMM2
#pragma unroll
    for (int m = 0; m < 4; ++m)
#pragma unroll
        for (int nn = 0; nn < 4; ++nn) acc[m][nn] = (f32x4){0.f, 0.f, 0.f, 0.f};
#pragma unroll
    for (int ks = 0; ks < 4; ++ks) {
        f16x8 a[4], b[4];
        int k0 = ks * 32 + lk * 8;
#pragma unroll
        for (int m = 0; m < 4; ++m) {
            int row = wm * 64 + m * 16 + l15;
            a[m] = *(const f16x8*)(As + row * D + (((ks * 4 + lk) ^ l15) << 3));
        }
#pragma unroll
        for (int nn = 0; nn < 4; ++nn) {
            int c = wn * 64 + nn * 16 + l15;
            b[nn] = *(const f16x8*)(Wt2 + (size_t)c * D + k0);
        }
#pragma unroll
        for (int m = 0; m < 4; ++m)
#pragma unroll
            for (int nn = 0; nn < 4; ++nn)
                acc[m][nn] =
                    __builtin_amdgcn_mfma_f32_16x16x32_f16(a[m], b[nn], acc[m][nn], 0, 0, 0);
    }
    __syncthreads();  // all GEMM2 LDS reads done before As reuse

    // epilogue2: h2 = relu(acc + b2) -> As (fp16, swizzled) + stats
    {
        float bc[4], cs[4] = {0.f, 0.f, 0.f, 0.f}, cq[4] = {0.f, 0.f, 0.f, 0.f};
#pragma unroll
        for (int nn = 0; nn < 4; ++nn) bc[nn] = b2[wn * 64 + nn * 16 + l15];
#pragma unroll
        for (int nn = 0; nn < 4; ++nn) {
            int c = wn * 64 + nn * 16 + l15;
            int chv = c >> 3, cw = c & 7;
#pragma unroll
            for (int m = 0; m < 4; ++m) {
                int rloc = wm * 64 + m * 16 + lk * 4;
#pragma unroll
                for (int r = 0; r < 4; ++r) {
                    float v = fmaxf(acc[m][nn][r] + bc[nn], 0.f);
                    As[(rloc + r) * D + ((chv ^ ((rloc + r) & 15)) << 3) + cw] = f2h(v);
                    if (rb + rloc + r < n) {
                        cs[nn] += v;
                        cq[nn] = fmaf(v, v, cq[nn]);
                    }
                }
            }
        }
#pragma unroll
        for (int nn = 0; nn < 4; ++nn) {
            int c = wn * 64 + nn * 16 + l15;
            atomicAdd(&sred[c], cs[nn]);
            atomicAdd(&sred[128 + c], cq[nn]);
        }
    }
    __syncthreads();

    // copy-out h2 (coalesced uint4)
#pragma unroll
    for (int i = 0; i < 8; ++i) {
        int idx = i * 256 + tid;
        int row = idx >> 4, ch = idx & 15;
        int g = rb + row;
        if (g < n) {
            uint4 v = *(const uint4*)(As + row * D + ((ch ^ (row & 15)) << 3));
            ((uint4*)h2)[(size_t)g * 16 + ch] = v;
        }
    }
    atomicAdd(&stats_mid[(blockIdx.x & 31) * 256 + tid], sred[tid]);
}

// ---------------- BN finalize -> affine (a,b) ----------------
__global__ __launch_bounds__(128) void k_bnfin(const float* __restrict__ sm,
                                               const float* __restrict__ gamma,
                                               const float* __restrict__ beta, float ninv,
                                               float* __restrict__ ss) {
    int c = threadIdx.x;
    float s = 0.f, q = 0.f;
    for (int r = 0; r < 32; ++r) {
        s += sm[r * 256 + c];
        q += sm[r * 256 + 128 + c];
    }
    float mean = s * ninv;
    float var = fmaxf(q * ninv - mean * mean, 0.f);
    float a = gamma[c] * rsqrtf(var + BN_EPS);
    ss[c] = a;
    ss[128 + c] = beta[c] - mean * a;
}

// ---------------- final normalize: out = a*h2 + b (fp32) ----------------
__global__ void k_norm_final(const uint* __restrict__ h2, const float* __restrict__ ss, int nd8,
                             float* __restrict__ out) {
    int i = blockIdx.x * blockDim.x + threadIdx.x;
    if (i >= nd8) return;
    size_t off = (size_t)i * 8;
    int c = (int)(off & (D - 1));
    uint4 v = *(const uint4*)(h2 + off / 2);
    float4 a0 = *(const float4*)(ss + c), a1 = *(const float4*)(ss + c + 4);
    float4 b0 = *(const float4*)(ss + 128 + c), b1 = *(const float4*)(ss + 132 + c);
    float4 o0, o1;
    o0.x = fmaf(hlo(v.x), a0.x, b0.x);
    o0.y = fmaf(hhi(v.x), a0.y, b0.y);
    o0.z = fmaf(hlo(v.y), a0.z, b0.z);
    o0.w = fmaf(hhi(v.y), a0.w, b0.w);
    o1.x = fmaf(hlo(v.z), a1.x, b1.x);
    o1.y = fmaf(hhi(v.z), a1.y, b1.y);
    o1.z = fmaf(hlo(v.w), a1.z, b1.z);
    o1.w = fmaf(hhi(v.w), a1.w, b1.w);
    *(float4*)(out + off) = o0;
    *(float4*)(out + off + 4) = o1;
}

extern "C" void kernel_launch(void* const* d_in, const int* in_sizes, int n_in, void* d_out,
                              int out_size, void* d_ws, size_t ws_size, hipStream_t stream) {
    const float* x = (const float*)d_in[0];
    const int* esrc = (const int*)d_in[1];
    const int* edst = (const int*)d_in[2];
    const float* W1 = (const float*)d_in[3];
    const float* b1 = (const float*)d_in[4];
    const float* W2 = (const float*)d_in[5];
    const float* b2 = (const float*)d_in[6];
    const float* gamma = (const float*)d_in[7];
    const float* beta = (const float*)d_in[8];

    const int N = in_sizes[0] / D;
    const int E = in_sizes[1];
    const int L = in_sizes[3] / (D * D);
    const size_t nd = (size_t)N * D;
    const int nd8 = (int)(nd / 8);
    const int nbkt = (N + BKT_N - 1) >> BKT_SH;
    const int CH = (E + ABLK - 1) / ABLK;

    // workspace layout (16B-aligned blocks first)
    char* ws = (char*)d_ws;
    uint* xh = (uint*)ws;          ws += nd * 2;                  // fp16 input
    uint* aggh = (uint*)ws;        ws += nd * 2;                  // fp16 raw agg
    uint* h2 = (uint*)ws;          ws += nd * 2;                  // fp16 activations
    ushort* Wt1 = (ushort*)ws;     ws += (size_t)L * D * D * 2;
    ushort* Wt2 = (ushort*)ws;     ws += (size_t)L * D * D * 2;
    uint* staged = (uint*)ws;      ws += (size_t)E * 4;
    int* col_idx = (int*)ws;       ws += (size_t)E * 4;
    int* bcnt = (int*)ws;          ws += 256 * ABLK * 4;
    int* boff = (int*)ws;          ws += 256 * ABLK * 4;
    float* stats_mid = (float*)ws; ws += 32 * 256 * 4;
    float* ssall = (float*)ws;     ws += (size_t)(L + 1) * 256 * 4;
    int* bbase = (int*)ws;         ws += (256 + 1) * 4;
    int* row_start = (int*)ws;     ws += (size_t)(N + 1) * 4;

    // ---- one-time prep ----
    k_convert<<<(nd8 + 255) / 256, 256, 0, stream>>>(x, xh, nd8);
    k_prep_w<<<L, 256, 0, stream>>>(W1, Wt1);
    k_prep_w<<<L, 256, 0, stream>>>(W2, Wt2);
    k_init_ss<<<1, 128, 0, stream>>>(ssall);

    // ---- bucketed CSR build ----
    k_bcount<<<ABLK, 256, 0, stream>>>(edst, E, CH, nbkt, bcnt);
    k_bscan<<<1, 256, 0, stream>>>(bcnt, nbkt, boff, bbase, row_start, N, E);
    k_bscatter<<<ABLK, 256, 0, stream>>>(esrc, edst, E, CH, nbkt, boff, bbase, staged);
    k_bfill<<<nbkt, 256, 0, stream>>>(staged, bbase, N, row_start, col_idx);

    const int gb = (N + 127) / 128;
    for (int l = 0; l < L; ++l) {
        const uint* src_act = (l == 0) ? xh : h2;
        k_gather<<<(N + 15) / 16, 256, 0, stream>>>(src_act, row_start, col_idx, N, aggh);
        k_zero_f<<<32, 256, 0, stream>>>(stats_mid, 32 * 256);
        k_mlp<<<gb, 256, 0, stream>>>((const ushort*)aggh, row_start, ssall + (size_t)l * 256,
                                      Wt1 + (size_t)l * D * D, b1 + (size_t)l * D,
                                      Wt2 + (size_t)l * D * D, b2 + (size_t)l * D, h2,
                                      stats_mid, N);
        k_bnfin<<<1, 128, 0, stream>>>(stats_mid, gamma + (size_t)l * D, beta + (size_t)l * D,
                                       1.0f / (float)N, ssall + (size_t)(l + 1) * 256);
    }
    k_norm_final<<<(nd8 + 255) / 256, 256, 0, stream>>>(h2, ssall + (size_t)L * 256, nd8,
                                                        (float*)d_out);
}